// Round 15
// baseline (72.386 us; speedup 1.0000x reference)
//
#include <hip/hip_runtime.h>

// Problem constants
#define B_    4
#define C_    64
#define H_    192
#define W_    640
#define D_    96     // disparities
#define TWB   128    // w1 columns per block
#define RWID  224    // staged R columns (TWB + 96)
#define NSLAB 5      // W / TWB
#define NDL   7      // 16-wide delta tiles covering d in [0,96)
#define HW_   (H_ * W_)
#define GP    132    // Gs pitch (floats), mult of 4, non-pow2
#define NWG   (NSLAB * B_ * H_)   // 3840 = 8 * 480

typedef __attribute__((ext_vector_type(8))) short short8;
typedef __attribute__((ext_vector_type(4))) float float4v;

// bank swizzle: spreads row bits into the 8x16B slot index of a 128B row
#define SWZ(x) ((((x) ^ ((x) >> 3)) & 7) << 3)

// packed f32x2 -> bf16x2 (single HW instruction, RTNE)
__device__ inline unsigned int pk2(float lo, float hi) {
    unsigned int r;
    asm("v_cvt_pk_bf16_f32 %0, %1, %2" : "=v"(r) : "v"(lo), "v"(hi));
    return r;
}

// out[b,0,d,h,w] = sum_c L[b,c,h,w] * R[b,c,h,(w - d*s) mod W] = G[w][w - s*d]
__global__ __launch_bounds__(512)
void cost_volume_mfma(const float* __restrict__ Lp,
                      const float* __restrict__ Rp,
                      const int* __restrict__ dirp,
                      float* __restrict__ out)
{
    const int s = dirp[0];   // +1 or -1, uniform across grid

    // 50688 B union:
    //   staging: Lb [128][64] u16 @ byte 0 (16 KB), Rb [224][64] u16 @ byte 16384 (28 KB)
    //   then reused as Gs [96][GP] f32 (50688 B)
    __shared__ unsigned int smem[12672];
    unsigned int* Lw = smem;                        // u32 view of Lb
    unsigned int* Rw = smem + 4096;                 // u32 view of Rb (byte 16384)
    const unsigned short* Lb = (const unsigned short*)smem;         // byte 0
    const unsigned short* Rb = (const unsigned short*)smem + 8192;  // byte 16384
    float* Gs = (float*)smem;

    // XCD-chunked bijective swizzle: NWG = 3840 = 8 * 480
    const int orig = blockIdx.x;
    const int nid  = (orig & 7) * (NWG / 8) + (orig >> 3);
    const int bh   = nid / NSLAB;
    const int slab = nid - bh * NSLAB;
    const int b  = bh / H_;
    const int h  = bh - b * H_;
    const int w0 = slab * TWB;
    const int rbase = (s == 1) ? (w0 - 96) : w0;    // global col of Rb k=0
    const int rbias = (s == 1) ? 96 : 0;            // B-frag tile bias

    const int tid = threadIdx.x;
    const float* Lrow = Lp + ((size_t)b * C_ * H_ + h) * W_;
    const float* Rrow = Rp + ((size_t)b * C_ * H_ + h) * W_;

    // ---- issue ALL staging loads first (MLP), statically-indexed regs ----
    // L: 4 float4/thread; R: up to 8 float4/thread (ragged)
    const int w4L = tid & 31;         // 0..31
    const int cL  = (tid >> 5) * 2;   // 0..30
    float4 pfL[4];
    {
        const float* p0 = Lrow + (size_t)cL * HW_ + w0 + 4 * w4L;
        pfL[0] = *(const float4*)(p0);
        pfL[1] = *(const float4*)(p0 + HW_);
        pfL[2] = *(const float4*)(p0 + (size_t)32 * HW_);
        pfL[3] = *(const float4*)(p0 + (size_t)33 * HW_);
    }
    float4 pfR[8];
    int  kR[4], cRp[4];
#pragma unroll
    for (int p = 0; p < 4; ++p) {
        const int idx = tid + 512 * p;           // 32 cpair x 56 k4 = 1792 units
        if (idx < 1792) {
            const int cp = idx / 56;
            const int k4 = idx - cp * 56;
            cRp[p] = 2 * cp;
            kR[p]  = k4;
            int col = rbase + 4 * k4;            // float4 never straddles wrap
            if (col < 0)   col += W_;
            if (col >= W_) col -= W_;
            const float* pc = Rrow + (size_t)(2 * cp) * HW_ + col;
            pfR[2 * p]     = *(const float4*)pc;
            pfR[2 * p + 1] = *(const float4*)(pc + HW_);
        }
    }
    __builtin_amdgcn_sched_barrier(0);   // keep loads issued above the converts

    // ---- convert + LDS staging writes ----
#pragma unroll
    for (int u0 = 0; u0 < 2; ++u0) {
        const int c = cL + 32 * u0;
        const float4 a = pfL[2 * u0], q = pfL[2 * u0 + 1];
        const float av[4] = {a.x, a.y, a.z, a.w};
        const float qv[4] = {q.x, q.y, q.z, q.w};
#pragma unroll
        for (int j = 0; j < 4; ++j) {
            const int w = 4 * w4L + j;
            Lw[w * 32 + ((c ^ SWZ(w)) >> 1)] = pk2(av[j], qv[j]);
        }
    }
#pragma unroll
    for (int p = 0; p < 4; ++p) {
        if (tid + 512 * p < 1792) {
            const float4 a = pfR[2 * p], q = pfR[2 * p + 1];
            const float av[4] = {a.x, a.y, a.z, a.w};
            const float qv[4] = {q.x, q.y, q.z, q.w};
            const int c = cRp[p];
#pragma unroll
            for (int j = 0; j < 4; ++j) {
                const int k = 4 * kR[p] + j;
                Rw[k * 32 + ((c ^ SWZ(k)) >> 1)] = pk2(av[j], qv[j]);
            }
        }
    }
    __syncthreads();   // staging visible

    // ---- MFMA: wave wv (0..7) owns w1 tile [w0+16wv, +16), 7 delta tiles x K=64 ----
    const int lane = tid & 63;
    const int wv   = tid >> 6;
    const int n15  = lane & 15;
    const int lg   = lane >> 4;

    short8 afrag[2];
    {
        const int w = 16 * wv + n15;
#pragma unroll
        for (int q = 0; q < 2; ++q) {
            const int c = lg * 8 + 32 * q;
            afrag[q] = *(const short8*)&Lb[w * 64 + (c ^ SWZ(w))];
        }
    }

    float4v acc[NDL];
#pragma unroll
    for (int dl = 0; dl < NDL; ++dl) acc[dl] = (float4v)0.f;

#pragma unroll
    for (int dl = 0; dl < NDL; ++dl) {
        const int k = rbias + 16 * wv - s * 16 * dl + n15;   // 0..223
#pragma unroll
        for (int q = 0; q < 2; ++q) {
            const int c = lg * 8 + 32 * q;
            const short8 bfrag = *(const short8*)&Rb[k * 64 + (c ^ SWZ(k))];
            acc[dl] = __builtin_amdgcn_mfma_f32_16x16x32_bf16(afrag[q], bfrag, acc[dl], 0, 0, 0);
        }
    }
    __syncthreads();   // staging reads done; safe to overwrite with Gs

    // ---- scatter into Gs[d][w_local] (pitch 132) ----
    // D layout (16x16x32): n = lane&15 (w2), m = (lane>>4)*4 + reg (w1)
#pragma unroll
    for (int dl = 0; dl < NDL; ++dl) {
#pragma unroll
        for (int r = 0; r < 4; ++r) {
            const int m = lg * 4 + r;
            const int d = 16 * dl + s * (m - n15);
            if (0 <= d && d < D_)
                Gs[d * GP + 16 * wv + m] = acc[dl][r];
        }
    }
    __syncthreads();   // Gs complete

    // ---- epilogue: float4 LDS reads, NON-TEMPORAL float4 global stores ----
    // output is written once and never re-read: bypass L2/L3 allocation so the
    // 252 MB input set stays L3-resident (the R13->R14 win, kept here)
    const int w4 = tid & 31;     // 32 float4 = 128 cols
    const int dg = tid >> 5;     // 16 d groups
#pragma unroll
    for (int p = 0; p < 6; ++p) {
        const int d = dg + 16 * p;
        const float4v v = *(const float4v*)&Gs[d * GP + 4 * w4];
        __builtin_nontemporal_store(
            v, (float4v*)(out + ((size_t)(b * D_ + d) * H_ + h) * W_ + w0 + 4 * w4));
    }
}

extern "C" void kernel_launch(void* const* d_in, const int* in_sizes, int n_in,
                              void* d_out, int out_size, void* d_ws, size_t ws_size,
                              hipStream_t stream)
{
    const float* un_l = (const float*)d_in[0];
    const float* un_r = (const float*)d_in[1];
    const int*   dirp = (const int*)d_in[2];
    float* out = (float*)d_out;

    dim3 grid(NWG);    // 3840
    dim3 block(512);

    // single kernel, runtime-uniform direction
    cost_volume_mfma<<<grid, block, 0, stream>>>(un_l, un_r, dirp, out);
}

// Round 16
// 71.863 us; speedup vs baseline: 1.0073x; 1.0073x over previous
//
#include <hip/hip_runtime.h>

// Problem constants
#define B_   4
#define C_   64
#define H_   192
#define W_   640
#define D_   96     // disparities
#define TWB  64     // w1 columns per block
#define NDL  7      // 16-wide delta tiles covering d in [0,96)
#define HW_  (H_ * W_)
#define GP   97     // Gs pitch: [w_local][d], odd -> bank = (w+d)%32, <=2-way
#define NWG  7680   // (W/TWB) * B * H = 8 * 960

typedef __attribute__((ext_vector_type(8))) short short8;
typedef __attribute__((ext_vector_type(4))) float float4v;

// bank swizzle: spreads row bits into the 8x16B slot index of a 128B row
#define SWZ(x) ((((x) ^ ((x) >> 3)) & 7) << 3)

// packed f32x2 -> bf16x2 (single HW instruction, RTNE)
__device__ inline unsigned int pk2(float lo, float hi) {
    unsigned int r;
    asm("v_cvt_pk_bf16_f32 %0, %1, %2" : "=v"(r) : "v"(lo), "v"(hi));
    return r;
}

// out[b,0,d,h,w] = sum_c L[b,c,h,w] * R[b,c,h,(w - d*s) mod W] = G[w][w - s*d]
__global__ __launch_bounds__(256)
void cost_volume_mfma(const float* __restrict__ Lp,
                      const float* __restrict__ Rp,
                      const int* __restrict__ dirp,
                      float* __restrict__ out)
{
    const int s = dirp[0];   // +1 or -1, uniform across grid

    // 28672 B union:
    //   staging: Lb [64][64] u16 @ byte 0, Rb [160][64] u16 @ byte 8192
    //   then reused as Gs [64 w][GP=97 d] f32 (24832 B)
    __shared__ unsigned int smem[7168];
    unsigned int* Lw = smem;
    unsigned int* Rw = smem + 2048;                 // byte 8192
    const unsigned short* Lb = (const unsigned short*)smem;         // byte 0
    const unsigned short* Rb = (const unsigned short*)smem + 4096;  // byte 8192
    float* Gs = (float*)smem;

    // XCD-chunked bijective swizzle: NWG = 7680 = 8 * 960
    const int orig = blockIdx.x;
    const int nid  = (orig & 7) * (NWG / 8) + (orig >> 3);
    const int bh   = nid / 10;
    const int slab = nid - bh * 10;
    const int b  = bh / H_;
    const int h  = bh - b * H_;
    const int w0 = slab * TWB;
    const int rbase = (s == 1) ? (w0 - 96) : w0;    // global col of Rb k=0
    const int rbias = (s == 1) ? 96 : 0;            // B-frag tile bias

    const int tid = threadIdx.x;
    const float* Lrow = Lp + ((size_t)b * C_ * H_ + h) * W_;
    const float* Rrow = Rp + ((size_t)b * C_ * H_ + h) * W_;

    const int w4 = tid & 15;          // L-stage + epilogue w group
    const int cL = (tid >> 4) * 2;    // L channel pair (0..30)
    const int k8 = tid & 7;           // R k4 low bits
    const int cR = (tid >> 3) * 2;    // R channel pair (0..62)

    // ---- issue ALL 14 stage loads first (MLP), statically-indexed regs ----
    float4 pf[14];
    {
        const float* p0 = Lrow + (size_t)cL * HW_ + w0 + 4 * w4;
        pf[0] = *(const float4*)(p0);
        pf[1] = *(const float4*)(p0 + HW_);
        pf[2] = *(const float4*)(p0 + (size_t)32 * HW_);
        pf[3] = *(const float4*)(p0 + (size_t)33 * HW_);
        const float* pc = Rrow + (size_t)cR * HW_;
#pragma unroll
        for (int u0 = 0; u0 < 5; ++u0) {
            int col = rbase + 4 * (k8 + 8 * u0);   // float4 never straddles wrap
            if (col < 0)   col += W_;
            if (col >= W_) col -= W_;
            pf[4 + 2 * u0] = *(const float4*)(pc + col);
            pf[5 + 2 * u0] = *(const float4*)(pc + HW_ + col);
        }
    }
    __builtin_amdgcn_sched_barrier(0);   // keep loads issued above the converts

    // ---- convert + LDS staging writes ----
#pragma unroll
    for (int u0 = 0; u0 < 2; ++u0) {
        const int c = cL + 32 * u0;
        const float4 a = pf[2 * u0], q = pf[2 * u0 + 1];
        const float av[4] = {a.x, a.y, a.z, a.w};
        const float qv[4] = {q.x, q.y, q.z, q.w};
#pragma unroll
        for (int j = 0; j < 4; ++j) {
            const int w = 4 * w4 + j;
            Lw[w * 32 + ((c ^ SWZ(w)) >> 1)] = pk2(av[j], qv[j]);
        }
    }
#pragma unroll
    for (int u0 = 0; u0 < 5; ++u0) {
        const float4 a = pf[4 + 2 * u0], q = pf[5 + 2 * u0];
        const float av[4] = {a.x, a.y, a.z, a.w};
        const float qv[4] = {q.x, q.y, q.z, q.w};
#pragma unroll
        for (int j = 0; j < 4; ++j) {
            const int k = 4 * (k8 + 8 * u0) + j;
            Rw[k * 32 + ((cR ^ SWZ(k)) >> 1)] = pk2(av[j], qv[j]);
        }
    }
    __syncthreads();   // staging visible

    // ---- MFMA: wave wv owns w1 tile [w0+16wv, +16), 7 delta tiles x K=64 ----
    const int lane = tid & 63;
    const int wv   = tid >> 6;
    const int n15  = lane & 15;
    const int lg   = lane >> 4;

    short8 afrag[2];
    {
        const int w = 16 * wv + n15;
#pragma unroll
        for (int q = 0; q < 2; ++q) {
            const int c = lg * 8 + 32 * q;
            afrag[q] = *(const short8*)&Lb[w * 64 + (c ^ SWZ(w))];
        }
    }

    float4v acc[NDL];
#pragma unroll
    for (int dl = 0; dl < NDL; ++dl) acc[dl] = (float4v)0.f;

#pragma unroll
    for (int dl = 0; dl < NDL; ++dl) {
        const int k = rbias + 16 * wv - s * 16 * dl + n15;   // 0..159
#pragma unroll
        for (int q = 0; q < 2; ++q) {
            const int c = lg * 8 + 32 * q;
            const short8 bfrag = *(const short8*)&Rb[k * 64 + (c ^ SWZ(k))];
            acc[dl] = __builtin_amdgcn_mfma_f32_16x16x32_bf16(afrag[q], bfrag, acc[dl], 0, 0, 0);
        }
    }
    __syncthreads();   // staging reads done; safe to overwrite with Gs

    // ---- scatter into Gs[w_local][d] (pitch 97, odd -> conflict-free) ----
    // D layout (16x16x32): n = lane&15 (w2), m = (lane>>4)*4 + reg (w1)
#pragma unroll
    for (int dl = 0; dl < NDL; ++dl) {
#pragma unroll
        for (int r = 0; r < 4; ++r) {
            const int m = lg * 4 + r;
            const int d = 16 * dl + s * (m - n15);
            if (0 <= d && d < D_)
                Gs[(16 * wv + m) * GP + d] = acc[dl][r];
        }
    }
    __syncthreads();   // Gs complete

    // ---- epilogue: scalar LDS reads (bank-clean), NON-TEMPORAL float4 stores
    // output lines are written once, never re-read: bypassing L2/L3 allocation
    // removed the hidden write-allocate fill reads (R13->R14: 95.6 -> 71.0 us)
    const int dg = tid >> 4;
#pragma unroll
    for (int p = 0; p < 6; ++p) {
        const int d = dg + 16 * p;
        float4v v;
        v[0] = Gs[(4 * w4 + 0) * GP + d];
        v[1] = Gs[(4 * w4 + 1) * GP + d];
        v[2] = Gs[(4 * w4 + 2) * GP + d];
        v[3] = Gs[(4 * w4 + 3) * GP + d];
        __builtin_nontemporal_store(
            v, (float4v*)(out + ((size_t)(b * D_ + d) * H_ + h) * W_ + w0 + 4 * w4));
    }
}

extern "C" void kernel_launch(void* const* d_in, const int* in_sizes, int n_in,
                              void* d_out, int out_size, void* d_ws, size_t ws_size,
                              hipStream_t stream)
{
    const float* un_l = (const float*)d_in[0];
    const float* un_r = (const float*)d_in[1];
    const int*   dirp = (const int*)d_in[2];
    float* out = (float*)d_out;

    dim3 grid(NWG);    // 7680
    dim3 block(256);

    // single kernel, runtime-uniform direction
    cost_volume_mfma<<<grid, block, 0, stream>>>(un_l, un_r, dirp, out);
}